// Round 1
// baseline (734.943 us; speedup 1.0000x reference)
//
#include <hip/hip_runtime.h>

// ---------------- problem constants ----------------
#define VOCAB 18
#define EMB   200
#define HID   200
#define G4    800           // 4*HID
#define SEQ   128
#define BATCH 2048
#define MB    8             // batch rows per block
#define NT    56            // N tiles of 16 -> 896 padded gate cols
#define KS    7             // K steps of 32 -> 224 padded K
#define TPB   512           // 8 waves
#define TPW   7             // W_hh tiles per wave (56/8)
#define TBL_COLS 896
#define LOGITS_N ((size_t)BATCH*SEQ*VOCAB)

typedef short s16x8 __attribute__((ext_vector_type(8)));
typedef float f32x4 __attribute__((ext_vector_type(4)));

__device__ __forceinline__ unsigned short f2bf(float f) {
  unsigned int u = __float_as_uint(f);
  u += 0x7FFFu + ((u >> 16) & 1u);            // RNE; no NaNs in this problem
  return (unsigned short)(u >> 16);
}
__device__ __forceinline__ float bf2f(unsigned short s) {
  return __uint_as_float(((unsigned int)s) << 16);
}
__device__ __forceinline__ float sigm(float x) {
  float e = __builtin_amdgcn_exp2f(x * 1.4426950408889634f);
  return e * __builtin_amdgcn_rcpf(e + 1.0f);
}
__device__ __forceinline__ float tanhq(float x) {
  float e = __builtin_amdgcn_exp2f(x * 2.8853900817779268f); // exp2(2x*log2e)
  return 1.0f - 2.0f * __builtin_amdgcn_rcpf(e + 1.0f);
}

// ---------------- prep: fold embedding+input-proj into table; pack W_hh/W_out
// into MFMA B-fragment order (lane l holds B[32s+8*(l>>4)+i][16n+(l&15)]) -----
__global__ void prep_kernel(const float* __restrict__ E, const float* __restrict__ W_ih,
                            const float* __restrict__ W_hh, const float* __restrict__ b_ih,
                            const float* __restrict__ b_hh, const float* __restrict__ W_out,
                            unsigned short* __restrict__ tbl, short* __restrict__ Wp,
                            short* __restrict__ Wop) {
  int tid = blockIdx.x * 256 + threadIdx.x;
  if (tid < VOCAB * TBL_COLS) {
    // table[v][col] = (v!=0)*dot(E[v], W_ih[col]) + b_ih[col] + b_hh[col]  (bf16)
    int v = tid / TBL_COLS, col = tid % TBL_COLS;
    float s = 0.f;
    if (col < G4) {
      s = b_ih[col] + b_hh[col];
      if (v != 0) {
        const float* Er = E + v * EMB;
        const float* Wr = W_ih + col * EMB;
        for (int e = 0; e < EMB; ++e) s += Er[e] * Wr[e];
      }
    }
    tbl[tid] = f2bf(s);
  } else if (tid < VOCAB*TBL_COLS + NT*KS*64) {
    int u = tid - VOCAB*TBL_COLS;
    int n   = u / (KS*64);
    int rem = u % (KS*64);
    int s_  = rem >> 6;
    int lane = rem & 63;
    int col = 16*n + (lane & 15);
    int kb  = lane >> 4;
    s16x8 o;
    #pragma unroll
    for (int i = 0; i < 8; ++i) {
      int k = 32*s_ + 8*kb + i;
      float f = (col < G4 && k < HID) ? W_hh[col*HID + k] : 0.f;
      o[i] = (short)f2bf(f);
    }
    *(s16x8*)(Wp + (size_t)u * 8) = o;
  } else if (tid < VOCAB*TBL_COLS + NT*KS*64 + 2*KS*64) {
    int u = tid - (VOCAB*TBL_COLS + NT*KS*64);
    int n   = u / (KS*64);
    int rem = u % (KS*64);
    int s_  = rem >> 6;
    int lane = rem & 63;
    int col = 16*n + (lane & 15);
    int kb  = lane >> 4;
    s16x8 o;
    #pragma unroll
    for (int i = 0; i < 8; ++i) {
      int k = 32*s_ + 8*kb + i;
      float f = (col < VOCAB && k < HID) ? W_out[col*HID + k] : 0.f;
      o[i] = (short)f2bf(f);
    }
    *(s16x8*)(Wop + (size_t)u * 8) = o;
  }
}

// ---------------- main: 256 blocks x 8 batch rows, full time loop per block.
// W_hh lives in VGPRs (49 bf16x8 frags/wave). gates-MFMA -> LDS -> elementwise
// -> h back into A-fragment layout in LDS. Logits fused on waves 0/1. --------
__global__ __launch_bounds__(TPB, 2)
void lstm_kernel(const int* __restrict__ x, const unsigned short* __restrict__ tbl,
                 const short* __restrict__ Wp, const short* __restrict__ Wop,
                 const float* __restrict__ b_out, float* __restrict__ out) {
  __shared__ unsigned short hA[KS*64*8];       // h in A-frag layout, bf16 (7.2KB)
  __shared__ float gatesL[MB*TBL_COLS];        // 28.7KB
  __shared__ float cL[MB*HID];                 // 6.4KB
  __shared__ int   xtok[MB*SEQ];               // 4KB

  const int tid  = threadIdx.x;
  const int lane = tid & 63;
  const int w    = tid >> 6;                   // wave 0..7
  const int blk  = blockIdx.x;
  const int l15  = lane & 15;
  const int rowq = (lane >> 4) << 2;           // 0,4,8,12
  const bool lo  = (lane < 32);                // lanes holding C rows 0..7

  for (int i = tid; i < KS*64*8; i += TPB) hA[i] = 0;      // h0 = 0 (+pad rows)
  for (int i = tid; i < MB*HID;  i += TPB) cL[i] = 0.f;    // c0 = 0
  for (int i = tid; i < MB*SEQ;  i += TPB) xtok[i] = x[blk*(MB*SEQ) + i];

  // W_hh fragments, resident for the whole kernel: 196 VGPRs/lane
  s16x8 wF[TPW][KS];
  #pragma unroll
  for (int n = 0; n < TPW; ++n) {
    #pragma unroll
    for (int s = 0; s < KS; ++s)
      wF[n][s] = *(const s16x8*)(Wp + ((((w*TPW + n)*KS) + s)*64 + lane) * 8);
  }

  float breg = 0.f;
  if (w < 2) { int v = 16*w + l15; breg = (v < VOCAB) ? b_out[v] : 0.f; }

  __syncthreads();

  for (int t = 0; t < SEQ; ++t) {
    // ---- phase A: gates = table[x[:,t]] + h_t @ W_hh^T (acc-init = gather) ----
    f32x4 acc[TPW];
    #pragma unroll
    for (int q = 0; q < 4; ++q) {
      int r = (rowq + q) & 7;                  // clamp for masked-off lanes
      int v = xtok[r*SEQ + t];
      #pragma unroll
      for (int n = 0; n < TPW; ++n) {
        int col = 16*(w*TPW + n) + l15;
        float tv = bf2f(tbl[v*TBL_COLS + col]);
        acc[n][q] = lo ? tv : 0.f;
      }
    }
    #pragma unroll
    for (int s = 0; s < KS; ++s) {
      s16x8 aF = *(const s16x8*)&hA[(s*64 + lane)*8];
      #pragma unroll
      for (int n = 0; n < TPW; ++n)
        acc[n] = __builtin_amdgcn_mfma_f32_16x16x32_bf16(aF, wF[n][s], acc[n], 0, 0, 0);
    }
    if (lo) {
      #pragma unroll
      for (int n = 0; n < TPW; ++n) {
        int col = 16*(w*TPW + n) + l15;
        #pragma unroll
        for (int q = 0; q < 4; ++q)
          gatesL[(rowq + q)*TBL_COLS + col] = acc[n][q];
      }
    }
    // ---- fused logits for step t-1 (h_t is still in hA); waves 0/1 only ----
    if (w < 2) {
      f32x4 a2; a2[0] = breg; a2[1] = breg; a2[2] = breg; a2[3] = breg;
      #pragma unroll
      for (int s = 0; s < KS; ++s) {
        s16x8 aF = *(const s16x8*)&hA[(s*64 + lane)*8];
        s16x8 wo = *(const s16x8*)(Wop + ((w*KS + s)*64 + lane)*8);
        a2 = __builtin_amdgcn_mfma_f32_16x16x32_bf16(aF, wo, a2, 0, 0, 0);
      }
      if (t > 0 && lo) {
        int v = 16*w + l15;
        if (v < VOCAB) {
          #pragma unroll
          for (int q = 0; q < 4; ++q) {
            size_t bg = (size_t)blk*MB + rowq + q;
            out[(bg*SEQ + (t-1))*VOCAB + v] = a2[q];
          }
        }
      }
    }
    __syncthreads();

    // ---- phase B: activations, c/h update, h -> hA (bf16, A-frag layout) ----
    #pragma unroll
    for (int it = 0; it < 4; ++it) {
      int p = tid + TPB*it;
      if (p < MB*HID) {
        int r = p / HID;
        int j = p - r*HID;
        float xi = gatesL[r*TBL_COLS + j];
        float xf = gatesL[r*TBL_COLS + j + 200];
        float xg = gatesL[r*TBL_COLS + j + 400];
        float xo = gatesL[r*TBL_COLS + j + 600];
        float co = cL[p];
        float i_ = sigm(xi);
        float f_ = sigm(xf);
        float g_ = tanhq(xg);
        float o_ = sigm(xo);
        float cn = f_*co + i_*g_;
        float h  = o_*tanhq(cn);
        cL[p] = cn;
        hA[((j>>5)*64 + (r + 16*((j>>3)&3)))*8 + (j&7)] = f2bf(h);
        if (t == SEQ-1) {
          size_t bg = (size_t)blk*MB + r;
          out[LOGITS_N + bg*HID + j] = h;                          // h_n (fp32)
          out[LOGITS_N + (size_t)BATCH*HID + bg*HID + j] = cn;     // c_n (fp32)
        }
      }
    }
    __syncthreads();
  }

  // ---- epilogue: logits for t = SEQ-1 from h_SEQ ----
  if (w < 2) {
    f32x4 a2; a2[0] = breg; a2[1] = breg; a2[2] = breg; a2[3] = breg;
    #pragma unroll
    for (int s = 0; s < KS; ++s) {
      s16x8 aF = *(const s16x8*)&hA[(s*64 + lane)*8];
      s16x8 wo = *(const s16x8*)(Wop + ((w*KS + s)*64 + lane)*8);
      a2 = __builtin_amdgcn_mfma_f32_16x16x32_bf16(aF, wo, a2, 0, 0, 0);
    }
    if (lo) {
      int v = 16*w + l15;
      if (v < VOCAB) {
        #pragma unroll
        for (int q = 0; q < 4; ++q) {
          size_t bg = (size_t)blk*MB + rowq + q;
          out[(bg*SEQ + (SEQ-1))*VOCAB + v] = a2[q];
        }
      }
    }
  }
}

extern "C" void kernel_launch(void* const* d_in, const int* in_sizes, int n_in,
                              void* d_out, int out_size, void* d_ws, size_t ws_size,
                              hipStream_t stream) {
  const int*   x     = (const int*)  d_in[0];
  const float* E     = (const float*)d_in[1];
  const float* W_ih  = (const float*)d_in[2];
  const float* W_hh  = (const float*)d_in[3];
  const float* b_ih  = (const float*)d_in[4];
  const float* b_hh  = (const float*)d_in[5];
  const float* W_out = (const float*)d_in[6];
  const float* b_out = (const float*)d_in[7];
  float* out = (float*)d_out;

  // ws layout (all 16B aligned): table 32256B | Wp 401408B | Wop 14336B  (~448KB)
  unsigned short* tbl = (unsigned short*)d_ws;
  short* Wp  = (short*)d_ws + VOCAB*TBL_COLS;
  short* Wop = Wp + (size_t)NT*KS*64*8;

  int prep_threads = VOCAB*TBL_COLS + NT*KS*64 + 2*KS*64;
  int prep_blocks  = (prep_threads + 255) / 256;
  prep_kernel<<<prep_blocks, 256, 0, stream>>>(E, W_ih, W_hh, b_ih, b_hh, W_out,
                                               tbl, Wp, Wop);
  lstm_kernel<<<BATCH/MB, TPB, 0, stream>>>(x, tbl, Wp, Wop, b_out, out);
}

// Round 2
// 497.460 us; speedup vs baseline: 1.4774x; 1.4774x over previous
//
#include <hip/hip_runtime.h>

// ---------------- problem constants ----------------
#define VOCAB 18
#define EMB   200
#define HID   200
#define G4    800           // 4*HID
#define SEQ   128
#define BATCH 2048
#define MB    8             // batch rows per block
#define NT    56            // N tiles of 16: 50 gate tiles + 2 W_out tiles + 4 zero
#define KS    7             // K steps of 32 -> 224 padded K
#define TPB   512           // 8 waves
#define TPW   7             // tiles per wave (56/8)
#define LOGITS_N ((size_t)BATCH*SEQ*VOCAB)

typedef short s16x8 __attribute__((ext_vector_type(8)));
typedef float f32x4 __attribute__((ext_vector_type(4)));

__device__ __forceinline__ unsigned short f2bf(float f) {
  unsigned int u = __float_as_uint(f);
  u += 0x7FFFu + ((u >> 16) & 1u);            // RNE; no NaNs in this problem
  return (unsigned short)(u >> 16);
}
__device__ __forceinline__ float bf2f(unsigned short s) {
  return __uint_as_float(((unsigned int)s) << 16);
}
__device__ __forceinline__ float sigm(float x) {
  float e = __builtin_amdgcn_exp2f(x * 1.4426950408889634f);
  return e * __builtin_amdgcn_rcpf(e + 1.0f);
}
__device__ __forceinline__ float tanhq(float x) {
  float e = __builtin_amdgcn_exp2f(x * 2.8853900817779268f); // exp2(2x*log2e)
  return 1.0f - 2.0f * __builtin_amdgcn_rcpf(e + 1.0f);
}

// ---------------- prep ----------------
// tbl[v][j] = (v!=0)*dot(E[v], W_ih[j]) + b_ih[j] + b_hh[j], bf16, 18x800.
// Wp: 56 tiles x 7 K-steps, B-frag order: lane l elem i = B[32s+8*(l>>4)+i][16n+(l&15)]
//   where B[k][col] = W_hh[col][k] for col<800, W_out[col-800][k] for 800<=col<818, else 0.
__global__ void prep_kernel(const float* __restrict__ E, const float* __restrict__ W_ih,
                            const float* __restrict__ W_hh, const float* __restrict__ b_ih,
                            const float* __restrict__ b_hh, const float* __restrict__ W_out,
                            unsigned short* __restrict__ tbl, short* __restrict__ Wp) {
  int tid = blockIdx.x * 256 + threadIdx.x;
  if (tid < VOCAB * G4) {
    int v = tid / G4, col = tid % G4;
    float s = b_ih[col] + b_hh[col];
    if (v != 0) {
      const float* Er = E + v * EMB;
      const float* Wr = W_ih + col * EMB;
      for (int e = 0; e < EMB; ++e) s += Er[e] * Wr[e];
    }
    tbl[tid] = f2bf(s);
  } else if (tid < VOCAB*G4 + NT*KS*64) {
    int u = tid - VOCAB*G4;
    int n    = u / (KS*64);
    int rem  = u % (KS*64);
    int s_   = rem >> 6;
    int lane = rem & 63;
    int col  = 16*n + (lane & 15);
    int kb   = lane >> 4;
    s16x8 o;
    #pragma unroll
    for (int i = 0; i < 8; ++i) {
      int k = 32*s_ + 8*kb + i;
      float f = 0.f;
      if (k < HID) {
        if (col < G4)            f = W_hh[col*HID + k];
        else if (col < G4+VOCAB) f = W_out[(col-G4)*HID + k];
      }
      o[i] = (short)f2bf(f);
    }
    *(s16x8*)(Wp + (size_t)u * 8) = o;
  }
}

// ---------------- main: 256 blocks x 8 batch rows; W_hh+W_out resident in
// VGPRs (49 frags = 196 VGPR/lane); gates+logits in ONE MFMA sweep. ----------
__global__ __launch_bounds__(TPB, 2)
void lstm_kernel(const int* __restrict__ x, const unsigned short* __restrict__ tbl,
                 const short* __restrict__ Wp, const float* __restrict__ b_out,
                 float* __restrict__ out) {
  __shared__ unsigned short hA[KS*64*8];       // h in A-frag layout, bf16 (7.2KB)
  __shared__ float gatesL[MB*G4];              // 25.6KB
  __shared__ int   xtok[MB*SEQ];               // 4KB

  const int tid  = threadIdx.x;
  const int lane = tid & 63;
  const int w    = tid >> 6;                   // wave 0..7
  const int blk  = blockIdx.x;
  const int l15  = lane & 15;
  const int rowq = (lane >> 4) << 2;           // C rows rowq..rowq+3 (lanes<32 real)
  const bool lo  = (lane < 32);                // lanes holding C rows 0..7

  for (int i = tid; i < KS*64*8; i += TPB) hA[i] = 0;      // h0 = 0 (+pad rows)
  for (int i = tid; i < MB*SEQ;  i += TPB) xtok[i] = x[blk*(MB*SEQ) + i];

  // resident weight fragments: 49 x 4 VGPR = 196 VGPR/lane
  s16x8 wF[TPW][KS];
  #pragma unroll
  for (int n = 0; n < TPW; ++n)
    #pragma unroll
    for (int s = 0; s < KS; ++s)
      wF[n][s] = *(const s16x8*)(Wp + ((((w*TPW + n)*KS) + s)*64 + lane) * 8);

  // b_out for the two logits tiles (only wave 7 uses)
  const float bo1 = (l15 < VOCAB)      ? b_out[l15]      : 0.f;
  const float bo2 = (16 + l15 < VOCAB) ? b_out[16 + l15] : 0.f;

  float creg[4] = {0.f, 0.f, 0.f, 0.f};        // c state, thread-resident

  __syncthreads();

  for (int t = 0; t < SEQ; ++t) {
    // ---- phase A: one MFMA sweep -> gates (tiles 0..49) + logits (50,51) ----
    f32x4 acc[TPW];
    #pragma unroll
    for (int n = 0; n < TPW; ++n) { acc[n][0]=0.f; acc[n][1]=0.f; acc[n][2]=0.f; acc[n][3]=0.f; }
    #pragma unroll
    for (int s = 0; s < KS; ++s) {
      s16x8 aF = *(const s16x8*)&hA[(s*64 + lane)*8];
      #pragma unroll
      for (int n = 0; n < TPW; ++n)
        acc[n] = __builtin_amdgcn_mfma_f32_16x16x32_bf16(aF, wF[n][s], acc[n], 0, 0, 0);
    }
    if (lo) {
      #pragma unroll
      for (int n = 0; n < TPW; ++n) {
        int col = 16*(w*TPW + n) + l15;
        if (col < G4) {
          #pragma unroll
          for (int q = 0; q < 4; ++q)
            gatesL[(rowq + q)*G4 + col] = acc[n][q];
        } else if (col < G4 + 32 && t > 0) {   // logits for step t-1
          int v = col - G4;
          if (v < VOCAB) {
            float bo = (v < 16) ? bo1 : bo2;
            #pragma unroll
            for (int q = 0; q < 4; ++q) {
              size_t bg = (size_t)blk*MB + rowq + q;
              out[(bg*SEQ + (t-1))*VOCAB + v] = acc[n][q] + bo;
            }
          }
        }
      }
    }
    __syncthreads();

    // ---- phase B: + table gather, activations, c/h update, h -> hA ----
    #pragma unroll
    for (int it = 0; it < 4; ++it) {
      int p = tid + TPB*it;
      if (p < MB*HID) {
        int r = p / HID;
        int j = p - r*HID;
        int v = xtok[r*SEQ + t];
        const unsigned short* tr = tbl + v*G4 + j;
        float xi = gatesL[r*G4 + j]       + bf2f(tr[0]);
        float xf = gatesL[r*G4 + j + 200] + bf2f(tr[200]);
        float xg = gatesL[r*G4 + j + 400] + bf2f(tr[400]);
        float xo = gatesL[r*G4 + j + 600] + bf2f(tr[600]);
        float i_ = sigm(xi);
        float f_ = sigm(xf);
        float g_ = tanhq(xg);
        float o_ = sigm(xo);
        float cn = f_*creg[it] + i_*g_;
        float h  = o_*tanhq(cn);
        creg[it] = cn;
        hA[((j>>5)*64 + (r + 16*((j>>3)&3)))*8 + (j&7)] = f2bf(h);
        if (t == SEQ-1) {
          size_t bg = (size_t)blk*MB + r;
          out[LOGITS_N + bg*HID + j] = h;                          // h_n
          out[LOGITS_N + (size_t)BATCH*HID + bg*HID + j] = cn;     // c_n
        }
      }
    }
    __syncthreads();
  }

  // ---- epilogue: logits for t = SEQ-1 from final h (wave 7's tiles 50/51) ----
  if (w == 7) {
    f32x4 a1, a2;
    a1[0]=0.f; a1[1]=0.f; a1[2]=0.f; a1[3]=0.f;
    a2[0]=0.f; a2[1]=0.f; a2[2]=0.f; a2[3]=0.f;
    #pragma unroll
    for (int s = 0; s < KS; ++s) {
      s16x8 aF = *(const s16x8*)&hA[(s*64 + lane)*8];
      a1 = __builtin_amdgcn_mfma_f32_16x16x32_bf16(aF, wF[1][s], a1, 0, 0, 0);
      a2 = __builtin_amdgcn_mfma_f32_16x16x32_bf16(aF, wF[2][s], a2, 0, 0, 0);
    }
    if (lo) {
      #pragma unroll
      for (int q = 0; q < 4; ++q) {
        size_t bg = (size_t)blk*MB + rowq + q;
        size_t base = (bg*SEQ + (SEQ-1))*VOCAB;
        if (l15 < VOCAB)      out[base + l15]      = a1[q] + bo1;
        if (16 + l15 < VOCAB) out[base + 16 + l15] = a2[q] + bo2;
      }
    }
  }
}

extern "C" void kernel_launch(void* const* d_in, const int* in_sizes, int n_in,
                              void* d_out, int out_size, void* d_ws, size_t ws_size,
                              hipStream_t stream) {
  const int*   x     = (const int*)  d_in[0];
  const float* E     = (const float*)d_in[1];
  const float* W_ih  = (const float*)d_in[2];
  const float* W_hh  = (const float*)d_in[3];
  const float* b_ih  = (const float*)d_in[4];
  const float* b_hh  = (const float*)d_in[5];
  const float* W_out = (const float*)d_in[6];
  const float* b_out = (const float*)d_in[7];
  float* out = (float*)d_out;

  // ws layout: tbl 18*800*2 = 28800B | Wp 56*7*64*8*2 = 401408B   (~430KB)
  unsigned short* tbl = (unsigned short*)d_ws;
  short* Wp = (short*)d_ws + VOCAB*G4;

  int prep_threads = VOCAB*G4 + NT*KS*64;
  int prep_blocks  = (prep_threads + 255) / 256;
  prep_kernel<<<prep_blocks, 256, 0, stream>>>(E, W_ih, W_hh, b_ih, b_hh, W_out,
                                               tbl, Wp);
  lstm_kernel<<<BATCH/MB, TPB, 0, stream>>>(x, tbl, Wp, b_out, out);
}